// Round 6
// baseline (335.650 us; speedup 1.0000x reference)
//
#include <hip/hip_runtime.h>
#include <math.h>

// Problem constants
constexpr int BB   = 16;
constexpr int NPGc = 4096;
constexpr int Cc   = 256;
constexpr int Nc   = BB * NPGc;      // 65536
constexpr int Ec   = Nc * 16;        // 1048576 = 1<<20
constexpr int Kc   = 1024;           // ceil(0.25*4096)
constexpr int NBUK = 512;            // dst buckets
constexpr int BUKW = 256;            // dst per bucket (2N / NBUK)
constexpr int CHUNK = 2048;          // edges per count/fill block
                                     // (r5: 8192 -> 384 blocks = 1.5/CU = occ 11%,
                                     //  latency-bound scatter; 2048 -> 1536 blocks = 6/CU)
constexpr int NCHUNK = (3 * Ec) / CHUNK;   // 1536

// ---------- monotonic float <-> u32 key ----------
__device__ __forceinline__ unsigned fkey(float f) {
    int b = __float_as_int(f);
    unsigned u = (unsigned)b;
    return (b < 0) ? ~u : (u | 0x80000000u);
}
__device__ __forceinline__ float inv_fkey(unsigned u) {
    unsigned b = (u & 0x80000000u) ? (u ^ 0x80000000u) : ~u;
    return __int_as_float((int)b);
}

// ---------- kernel 1: kqv = x @ w + b (fp32), ONE SIDE per dispatch ----------
// Round-3 proven body (VGPR 52, ~23.5us/side).
__global__ __launch_bounds__(256) void kqv_side_kernel(
    const float* __restrict__ x, const float* __restrict__ w,
    const float* __restrict__ bp,
    float2* __restrict__ kv, float* __restrict__ qg)
{
    __shared__ float wls[768];                     // 256x3 weights, 3 KB
    int tid  = threadIdx.x;
    int wave = tid >> 6, lane = tid & 63;
    int grp  = lane >> 4, l = lane & 15;
    int g    = blockIdx.x * 16 + wave * 4 + grp;   // group id, 2 rows each
    int node0 = g * 2;                             // 0..N-1

    if (tid < 192)
        ((float4*)wls)[tid] = ((const float4*)w)[tid];
    float b0 = bp[0], b1 = bp[1], b2 = bp[2];
    __syncthreads();

    // all 8 x-loads issued up front (32 VGPRs of payload)
    const float4* rp = (const float4*)(x + (size_t)node0 * Cc);
    float4 xv[2][4];
#pragma unroll
    for (int r = 0; r < 2; ++r)
#pragma unroll
        for (int it = 0; it < 4; ++it)
            xv[r][it] = rp[r * 64 + it * 16 + l];

    float kk[2] = {0.f, 0.f};
    float qq[2] = {0.f, 0.f};
    float vv[2] = {0.f, 0.f};
    const float4* wv4 = (const float4*)wls;
#pragma unroll
    for (int it = 0; it < 4; ++it) {
        float4 w0 = wv4[it * 48 + l * 3 + 0];
        float4 w1 = wv4[it * 48 + l * 3 + 1];
        float4 w2 = wv4[it * 48 + l * 3 + 2];
#pragma unroll
        for (int r = 0; r < 2; ++r) {
            float x0 = xv[r][it].x, x1 = xv[r][it].y;
            float x2 = xv[r][it].z, x3 = xv[r][it].w;
            kk[r] = fmaf(x0, w0.x, kk[r]);
            qq[r] = fmaf(x0, w0.y, qq[r]);
            vv[r] = fmaf(x0, w0.z, vv[r]);
            kk[r] = fmaf(x1, w0.w, kk[r]);
            qq[r] = fmaf(x1, w1.x, qq[r]);
            vv[r] = fmaf(x1, w1.y, vv[r]);
            kk[r] = fmaf(x2, w1.z, kk[r]);
            qq[r] = fmaf(x2, w1.w, qq[r]);
            vv[r] = fmaf(x2, w2.x, vv[r]);
            kk[r] = fmaf(x3, w2.y, kk[r]);
            qq[r] = fmaf(x3, w2.z, qq[r]);
            vv[r] = fmaf(x3, w2.w, vv[r]);
        }
    }

#pragma unroll
    for (int r = 0; r < 2; ++r) {
#pragma unroll
        for (int off = 8; off; off >>= 1) {
            kk[r] += __shfl_xor(kk[r], off, 64);
            qq[r] += __shfl_xor(qq[r], off, 64);
            vv[r] += __shfl_xor(vv[r], off, 64);
        }
        if (l == 0) {
            int node = node0 + r;
            kv[node] = make_float2(kk[r] + b0, vv[r] + b2);
            qg[node] = qq[r] + b1;
        }
    }
}

// ---------- kernel 2a: per-bucket edge counts (int4 loads) ----------
__global__ __launch_bounds__(256) void count_kernel(
    const int* __restrict__ ei0, const int* __restrict__ ei1,
    const int* __restrict__ ei2, unsigned* __restrict__ bucket_cnt)
{
    __shared__ unsigned hist[NBUK];
    int tid = threadIdx.x;
    for (int j = tid; j < NBUK; j += 256) hist[j] = 0;
    __syncthreads();
    unsigned base = blockIdx.x * (unsigned)CHUNK;
    int t = (int)(base >> 20);
    unsigned i0 = base & (unsigned)(Ec - 1);
    const int* ei = (t == 0) ? ei0 : (t == 1) ? ei1 : ei2;
    int off = (t == 0) ? Nc : 0;
    const int4* dv = (const int4*)(ei + Ec + i0);
#pragma unroll
    for (int j = 0; j < CHUNK / 1024; ++j) {
        int4 d4 = dv[j * 256 + tid];
        atomicAdd(&hist[(unsigned)(d4.x + off) >> 8], 1u);
        atomicAdd(&hist[(unsigned)(d4.y + off) >> 8], 1u);
        atomicAdd(&hist[(unsigned)(d4.z + off) >> 8], 1u);
        atomicAdd(&hist[(unsigned)(d4.w + off) >> 8], 1u);
    }
    __syncthreads();
    for (int j = tid; j < NBUK; j += 256)
        if (hist[j]) atomicAdd(&bucket_cnt[j], hist[j]);
}

// ---------- kernel 2b: exclusive scan of bucket counts ----------
__global__ __launch_bounds__(NBUK) void scan_kernel(
    const unsigned* __restrict__ bucket_cnt,
    unsigned* __restrict__ bucket_base, unsigned* __restrict__ bucket_fill)
{
    __shared__ unsigned s[NBUK];
    int t = threadIdx.x;
    unsigned mine = bucket_cnt[t];
    s[t] = mine;
    __syncthreads();
    for (int off = 1; off < NBUK; off <<= 1) {
        unsigned v = (t >= off) ? s[t - off] : 0u;
        __syncthreads();
        s[t] += v;
        __syncthreads();
    }
    unsigned ex = s[t] - mine;
    bucket_base[t] = ex;
    bucket_fill[t] = ex;
    if (t == NBUK - 1) bucket_base[NBUK] = s[t];
}

// ---------- kernel 2c: scatter packed records into bucket order ----------
// record = s(16 bits) | t<<16 | (dg&255)<<18
// v3: CHUNK 2048 (6 blocks/CU for scatter latency hiding); dst kept in regs.
__global__ __launch_bounds__(256) void fill_kernel(
    const int* __restrict__ ei0, const int* __restrict__ ei1,
    const int* __restrict__ ei2, unsigned* __restrict__ bucket_fill,
    unsigned* __restrict__ sorted)
{
    __shared__ unsigned hist[NBUK];
    __shared__ unsigned res[NBUK];
    int tid = threadIdx.x;
    for (int j = tid; j < NBUK; j += 256) hist[j] = 0;
    __syncthreads();
    unsigned base = blockIdx.x * (unsigned)CHUNK;
    int t = (int)(base >> 20);
    unsigned i0 = base & (unsigned)(Ec - 1);
    const int* ei = (t == 0) ? ei0 : (t == 1) ? ei1 : ei2;
    int off = (t == 0) ? Nc : 0;
    const int4* dv = (const int4*)(ei + Ec + i0);
    const int4* sv = (const int4*)(ei + i0);
    int4 dreg[CHUNK / 1024];
#pragma unroll
    for (int j = 0; j < CHUNK / 1024; ++j) {
        int4 d4 = dv[j * 256 + tid];
        dreg[j] = d4;
        atomicAdd(&hist[(unsigned)(d4.x + off) >> 8], 1u);
        atomicAdd(&hist[(unsigned)(d4.y + off) >> 8], 1u);
        atomicAdd(&hist[(unsigned)(d4.z + off) >> 8], 1u);
        atomicAdd(&hist[(unsigned)(d4.w + off) >> 8], 1u);
    }
    __syncthreads();
    for (int j = tid; j < NBUK; j += 256) {
        unsigned h = hist[j];
        // res = absolute base slot for this block's run in bucket j
        res[j] = h ? atomicAdd(&bucket_fill[j], h) : 0u;
    }
    __syncthreads();
#pragma unroll
    for (int j = 0; j < CHUNK / 1024; ++j) {
        int4 d4 = dreg[j];
        int4 s4 = sv[j * 256 + tid];
        int dd[4] = {d4.x, d4.y, d4.z, d4.w};
        int ss[4] = {s4.x, s4.y, s4.z, s4.w};
#pragma unroll
        for (int u = 0; u < 4; ++u) {
            int dg  = dd[u] + off;
            int bkt = dg >> 8;
            unsigned pos = atomicAdd(&res[bkt], 1u);  // returning LDS atomic
            sorted[pos] =
                (unsigned)ss[u] | ((unsigned)t << 16) | ((unsigned)(dg & 255) << 18);
        }
    }
}

// ---------- kernel 2d: per-bucket LDS accumulation (fp32, 2x replicated) ----------
__global__ __launch_bounds__(512) void bucket_accum_kernel(
    const unsigned* __restrict__ bucket_base, const unsigned* __restrict__ sorted,
    const float* __restrict__ krel_w, const float* __restrict__ krel_b,
    const float* __restrict__ vrel_w, const float* __restrict__ vrel_b,
    const float* __restrict__ p_rel,
    const float2* __restrict__ kv_i, const float2* __restrict__ kv_d,
    const float* __restrict__ q_glob,
    float* __restrict__ den, float* __restrict__ num)
{
    __shared__ float den_l[2 * BUKW];   // [dst][rep] interleaved: adjacent banks
    __shared__ float num_l[2 * BUKW];
    __shared__ float q_l[BUKW];
    int tid = threadIdx.x;
    int b   = blockIdx.x;
    den_l[tid] = 0.0f; num_l[tid] = 0.0f;      // 512 entries each
    if (tid < BUKW) q_l[tid] = q_glob[b * BUKW + tid];
    float kw0 = krel_w[0], kw1 = krel_w[1], kw2 = krel_w[2];
    float kb0 = krel_b[0], kb1 = krel_b[1], kb2 = krel_b[2];
    float vw0 = vrel_w[0], vw1 = vrel_w[1], vw2 = vrel_w[2];
    float vb0 = vrel_b[0], vb1 = vrel_b[1], vb2 = vrel_b[2];
    float pr0 = p_rel[0],  pr1 = p_rel[1],  pr2 = p_rel[2];
    unsigned beg = bucket_base[b], end = bucket_base[b + 1];
    int rep = tid & 1;
    __syncthreads();

    for (unsigned e = beg + tid; e < end; e += 512) {
        unsigned r = sorted[e];
        int s    = (int)(r & 0xFFFFu);
        int t    = (int)((r >> 16) & 3u);
        int low8 = (int)((r >> 18) & 255u);
        float2 kvv = (t == 1) ? kv_d[s] : kv_i[s];
        float kwt = (t == 0) ? kw0 : (t == 1) ? kw1 : kw2;
        float kbt = (t == 0) ? kb0 : (t == 1) ? kb1 : kb2;
        float vwt = (t == 0) ? vw0 : (t == 1) ? vw1 : vw2;
        float vbt = (t == 0) ? vb0 : (t == 1) ? vb1 : vb2;
        float prt = (t == 0) ? pr0 : (t == 1) ? pr1 : pr2;
        float ke = fmaf(kvv.x, kwt, kbt);
        float ve = fmaf(kvv.y, vwt, vbt);
        float logit = q_l[low8] * ke * prt;
        float ex = __expf(fminf(logit, 80.0f));
        int slot = low8 * 2 + rep;
        __hip_atomic_fetch_add(&den_l[slot], ex, __ATOMIC_RELAXED,
                               __HIP_MEMORY_SCOPE_WORKGROUP);
        __hip_atomic_fetch_add(&num_l[slot], ex * ve, __ATOMIC_RELAXED,
                               __HIP_MEMORY_SCOPE_WORKGROUP);
    }
    __syncthreads();
    if (tid < BUKW) {
        den[b * BUKW + tid] = den_l[tid * 2] + den_l[tid * 2 + 1];
        num[b * BUKW + tid] = num_l[tid * 2] + num_l[tid * 2 + 1];
    }
}

// ---------- kernel 3: score + 2-level radix top-K (u32 keys) ----------
__global__ __launch_bounds__(1024) void select_kernel(
    const float* __restrict__ den, const float* __restrict__ num,
    const float* __restrict__ w_out_inst, const float* __restrict__ b_out_inst,
    const float* __restrict__ w_out_data, const float* __restrict__ b_out_data,
    int* __restrict__ sel_idx, float* __restrict__ sel_w)
{
    __shared__ unsigned keys[NPGc];             // 16 KB
    __shared__ unsigned hist[2048];             // 8 KB
    __shared__ unsigned wsum[16];
    __shared__ unsigned short cand[NPGc];       // 8 KB
    __shared__ unsigned sh_bin1, sh_rem1, sh_bin2, sh_rem2, sh_cnt, sh_nc;

    int tid  = threadIdx.x;
    int seg  = blockIdx.x;          // 0..31
    int side = seg >> 4;
    int b    = seg & 15;
    float wo = side ? w_out_data[0] : w_out_inst[0];
    float bo = side ? b_out_data[0] : b_out_inst[0];
    int base_node = side * Nc + b * NPGc;
    int base_sel  = seg * Kc;

    unsigned myk[4]; int myj[4];
#pragma unroll
    for (int p = 0; p < 4; ++p) {
        int j = p * 1024 + tid;
        float dn = den[base_node + j];
        float a  = (dn > 0.0f) ? num[base_node + j] / dn : 0.0f;
        float z  = fmaf(a, wo, bo);
        float s  = 0.5f * z * (1.0f + erff(z * 0.70710678f));
        unsigned k32 = fkey(s);
        keys[j] = k32; myk[p] = k32; myj[p] = j;
    }
    if (tid == 0) { sh_cnt = 0; sh_nc = 0; }
    hist[tid] = 0; hist[tid + 1024] = 0;
    __syncthreads();

    // phase 1: hist over bits [31:21]
#pragma unroll
    for (int p = 0; p < 4; ++p) atomicAdd(&hist[myk[p] >> 21], 1u);
    __syncthreads();
    {
        unsigned g0 = hist[2047 - 2 * tid];
        unsigned g1 = hist[2046 - 2 * tid];
        unsigned x = g0 + g1;
        int lane = tid & 63;
#pragma unroll
        for (int off = 1; off < 64; off <<= 1) {
            unsigned y = __shfl_up(x, off, 64);
            if (lane >= off) x += y;
        }
        if (lane == 63) wsum[tid >> 6] = x;
        __syncthreads();
        if (tid < 16) {
            unsigned v = wsum[tid];
#pragma unroll
            for (int off = 1; off < 16; off <<= 1) {
                unsigned y = __shfl_up(v, off, 64);
                if (tid >= off) v += y;
            }
            wsum[tid] = v;
        }
        __syncthreads();
        unsigned basew = (tid >= 64) ? wsum[(tid >> 6) - 1] : 0u;
        unsigned incl  = basew + x;
        unsigned incl0 = incl - g1;
        unsigned K = Kc;
        if (incl0 >= K && incl0 - g0 < K) { sh_bin1 = 2047 - 2 * tid; sh_rem1 = K - (incl0 - g0); }
        if (incl  >= K && incl0     < K) { sh_bin1 = 2046 - 2 * tid; sh_rem1 = K - incl0; }
    }
    __syncthreads();
    unsigned bin1 = sh_bin1, rem1 = sh_rem1;
    hist[tid] = 0; hist[tid + 1024] = 0;
    __syncthreads();

    // phase 2: hist over bits [20:10] among bin1 keys
#pragma unroll
    for (int p = 0; p < 4; ++p)
        if ((myk[p] >> 21) == bin1)
            atomicAdd(&hist[(myk[p] >> 10) & 2047u], 1u);
    __syncthreads();
    {
        unsigned g0 = hist[2047 - 2 * tid];
        unsigned g1 = hist[2046 - 2 * tid];
        unsigned x = g0 + g1;
        int lane = tid & 63;
#pragma unroll
        for (int off = 1; off < 64; off <<= 1) {
            unsigned y = __shfl_up(x, off, 64);
            if (lane >= off) x += y;
        }
        if (lane == 63) wsum[tid >> 6] = x;
        __syncthreads();
        if (tid < 16) {
            unsigned v = wsum[tid];
#pragma unroll
            for (int off = 1; off < 16; off <<= 1) {
                unsigned y = __shfl_up(v, off, 64);
                if (tid >= off) v += y;
            }
            wsum[tid] = v;
        }
        __syncthreads();
        unsigned basew = (tid >= 64) ? wsum[(tid >> 6) - 1] : 0u;
        unsigned incl  = basew + x;
        unsigned incl0 = incl - g1;
        unsigned K = rem1;
        if (incl0 >= K && incl0 - g0 < K) { sh_bin2 = 2047 - 2 * tid; sh_rem2 = K - (incl0 - g0); }
        if (incl  >= K && incl0     < K) { sh_bin2 = 2046 - 2 * tid; sh_rem2 = K - incl0; }
    }
    __syncthreads();
    unsigned pref22 = (bin1 << 11) | sh_bin2;
    unsigned rem2 = sh_rem2;

    // phase 3: classify
#pragma unroll
    for (int p = 0; p < 4; ++p) {
        unsigned top22 = myk[p] >> 10;
        if (top22 > pref22) {
            unsigned pos = atomicAdd(&sh_cnt, 1u);
            sel_idx[base_sel + pos] = myj[p];
            sel_w[base_sel + pos]   = tanhf(inv_fkey(myk[p]));
        } else if (top22 == pref22) {
            unsigned cp = atomicAdd(&sh_nc, 1u);
            cand[cp] = (unsigned short)myj[p];
        }
    }
    __syncthreads();

    // phase 4: exact rank among candidates (key desc, index asc)
    unsigned nc = sh_nc;
    for (unsigned c = tid; c < nc; c += 1024) {
        int j = cand[c];
        unsigned k32 = keys[j];
        unsigned rank = 0;
        for (unsigned q = 0; q < nc; ++q) {
            int jq = cand[q];
            unsigned kq = keys[jq];
            rank += (kq > k32 || (kq == k32 && jq < j)) ? 1u : 0u;
        }
        if (rank < rem2) {
            unsigned pos = atomicAdd(&sh_cnt, 1u);
            sel_idx[base_sel + pos] = j;
            sel_w[base_sel + pos]   = tanhf(inv_fkey(k32));
        }
    }
}

// ---------- kernel 4: weighted mean of selected rows ----------
__global__ __launch_bounds__(1024) void pool_kernel(
    const float* __restrict__ x_inst, const float* __restrict__ x_data,
    const int* __restrict__ sel_idx, const float* __restrict__ sel_w,
    float* __restrict__ out)
{
    __shared__ int   ridx[64];
    __shared__ float rw[64];
    __shared__ float accs[256];
    int tid   = threadIdx.x;
    int blk   = blockIdx.x;
    int seg   = blk >> 4;
    int chunk = blk & 15;
    int side  = seg >> 4;
    int b     = seg & 15;
    if (tid < 64) {
        ridx[tid] = sel_idx[seg * Kc + chunk * 64 + tid];
        rw[tid]   = sel_w[seg * Kc + chunk * 64 + tid];
    }
    if (tid < 256) accs[tid] = 0.0f;
    __syncthreads();
    const float* x = side ? x_data : x_inst;
    int w = tid >> 6, l = tid & 63;
    float ax = 0.f, ay = 0.f, az = 0.f, aw = 0.f;
#pragma unroll
    for (int r = 0; r < 4; ++r) {
        int   row = ridx[w * 4 + r];
        float wt  = rw[w * 4 + r];
        float4 xv = ((const float4*)(x + ((size_t)(b * NPGc + row)) * Cc))[l];
        ax = fmaf(xv.x, wt, ax); ay = fmaf(xv.y, wt, ay);
        az = fmaf(xv.z, wt, az); aw = fmaf(xv.w, wt, aw);
    }
    atomicAdd(&accs[l * 4 + 0], ax);
    atomicAdd(&accs[l * 4 + 1], ay);
    atomicAdd(&accs[l * 4 + 2], az);
    atomicAdd(&accs[l * 4 + 3], aw);
    __syncthreads();
    if (tid < 256)
        unsafeAtomicAdd(&out[b * 512 + side * 256 + tid], accs[tid] * (1.0f / (float)Kc));
}

extern "C" void kernel_launch(void* const* d_in, const int* in_sizes, int n_in,
                              void* d_out, int out_size, void* d_ws, size_t ws_size,
                              hipStream_t stream) {
    const float* x_inst     = (const float*)d_in[0];
    const float* x_data     = (const float*)d_in[1];
    const float* w_kqv_inst = (const float*)d_in[2];
    const float* b_kqv_inst = (const float*)d_in[3];
    const float* w_kqv_data = (const float*)d_in[4];
    const float* b_kqv_data = (const float*)d_in[5];
    const float* w_out_inst = (const float*)d_in[6];
    const float* b_out_inst = (const float*)d_in[7];
    const float* w_out_data = (const float*)d_in[8];
    const float* b_out_data = (const float*)d_in[9];
    const float* krel_w     = (const float*)d_in[10];
    const float* krel_b     = (const float*)d_in[11];
    const float* vrel_w     = (const float*)d_in[12];
    const float* vrel_b     = (const float*)d_in[13];
    const float* p_rel      = (const float*)d_in[14];
    const int*   ei_i2d     = (const int*)d_in[15];
    const int*   ei_d2i     = (const int*)d_in[16];
    const int*   ei_i2i     = (const int*)d_in[17];
    float* out = (float*)d_out;

    // workspace layout (fp32) — ~15.4 MB
    char* ws = (char*)d_ws;
    float2* kv_i   = (float2*)ws;                        // N
    float2* kv_d   = kv_i + Nc;                          // N
    float*  q_glob = (float*)(kv_d + Nc);                // 2N
    float*  den    = q_glob + 2 * Nc;                    // 2N
    float*  num    = den + 2 * Nc;                       // 2N
    unsigned* bucket_cnt  = (unsigned*)(num + 2 * Nc);   // NBUK
    unsigned* bucket_base = bucket_cnt + NBUK;           // NBUK+1
    unsigned* bucket_fill = bucket_base + NBUK + 1;      // NBUK
    int*      sel_idx     = (int*)(bucket_fill + NBUK);  // 32*K
    float*    sel_w       = (float*)(sel_idx + 32 * Kc); // 32*K
    unsigned* sorted      = (unsigned*)(sel_w + 32 * Kc);// 3E (12.6 MB)

    hipMemsetAsync(bucket_cnt, 0, NBUK * sizeof(unsigned), stream);
    hipMemsetAsync(d_out, 0, (size_t)out_size * sizeof(float), stream);

    // edge path (independent of x): count -> scan -> fill
    count_kernel<<<NCHUNK, 256, 0, stream>>>(ei_i2d, ei_d2i, ei_i2i, bucket_cnt);
    scan_kernel<<<1, NBUK, 0, stream>>>(bucket_cnt, bucket_base, bucket_fill);
    fill_kernel<<<NCHUNK, 256, 0, stream>>>(ei_i2d, ei_d2i, ei_i2i,
                                            bucket_fill, sorted);

    // kqv per side: 32 rows per block, 2048 blocks each
    kqv_side_kernel<<<Nc / 32, 256, 0, stream>>>(
        x_inst, w_kqv_inst, b_kqv_inst, kv_i, q_glob);
    kqv_side_kernel<<<Nc / 32, 256, 0, stream>>>(
        x_data, w_kqv_data, b_kqv_data, kv_d, q_glob + Nc);

    // per-bucket LDS accumulate: 512 blocks x 512 threads
    bucket_accum_kernel<<<NBUK, 512, 0, stream>>>(
        bucket_base, sorted,
        krel_w, krel_b, vrel_w, vrel_b, p_rel,
        kv_i, kv_d, q_glob, den, num);

    // score + top-K select
    select_kernel<<<32, 1024, 0, stream>>>(
        den, num, w_out_inst, b_out_inst, w_out_data, b_out_data,
        sel_idx, sel_w);

    // pooled weighted mean
    pool_kernel<<<512, 1024, 0, stream>>>(x_inst, x_data, sel_idx, sel_w, out);
}

// Round 7
// 301.022 us; speedup vs baseline: 1.1150x; 1.1150x over previous
//
#include <hip/hip_runtime.h>
#include <math.h>

// Problem constants
constexpr int BB   = 16;
constexpr int NPGc = 4096;
constexpr int Cc   = 256;
constexpr int Nc   = BB * NPGc;      // 65536
constexpr int Ec   = Nc * 16;        // 1048576 = 1<<20
constexpr int Kc   = 1024;           // ceil(0.25*4096)
constexpr int NBUK = 512;            // dst buckets
constexpr int BUKW = 256;            // dst per bucket (2N / NBUK)
constexpr int CHUNK = 8192;          // edges per count/fill block (8192 = best write
                                     // coalescing; r6 showed smaller chunks fragment writes)
constexpr int NCHUNK = (3 * Ec) / CHUNK;   // 384
constexpr int ETHREADS = 1024;       // 16 waves/block: decouple occupancy from chunk size
                                     // (r5: 256t -> 6 waves/CU, occ 11%, latency-bound)

// ---------- monotonic float <-> u32 key ----------
__device__ __forceinline__ unsigned fkey(float f) {
    int b = __float_as_int(f);
    unsigned u = (unsigned)b;
    return (b < 0) ? ~u : (u | 0x80000000u);
}
__device__ __forceinline__ float inv_fkey(unsigned u) {
    unsigned b = (u & 0x80000000u) ? (u ^ 0x80000000u) : ~u;
    return __int_as_float((int)b);
}

// ---------- kernel 1: kqv = x @ w + b (fp32), ONE SIDE per dispatch ----------
// Round-3 proven body (VGPR 52, ~23.5us/side).
__global__ __launch_bounds__(256) void kqv_side_kernel(
    const float* __restrict__ x, const float* __restrict__ w,
    const float* __restrict__ bp,
    float2* __restrict__ kv, float* __restrict__ qg)
{
    __shared__ float wls[768];                     // 256x3 weights, 3 KB
    int tid  = threadIdx.x;
    int wave = tid >> 6, lane = tid & 63;
    int grp  = lane >> 4, l = lane & 15;
    int g    = blockIdx.x * 16 + wave * 4 + grp;   // group id, 2 rows each
    int node0 = g * 2;                             // 0..N-1

    if (tid < 192)
        ((float4*)wls)[tid] = ((const float4*)w)[tid];
    float b0 = bp[0], b1 = bp[1], b2 = bp[2];
    __syncthreads();

    // all 8 x-loads issued up front (32 VGPRs of payload)
    const float4* rp = (const float4*)(x + (size_t)node0 * Cc);
    float4 xv[2][4];
#pragma unroll
    for (int r = 0; r < 2; ++r)
#pragma unroll
        for (int it = 0; it < 4; ++it)
            xv[r][it] = rp[r * 64 + it * 16 + l];

    float kk[2] = {0.f, 0.f};
    float qq[2] = {0.f, 0.f};
    float vv[2] = {0.f, 0.f};
    const float4* wv4 = (const float4*)wls;
#pragma unroll
    for (int it = 0; it < 4; ++it) {
        float4 w0 = wv4[it * 48 + l * 3 + 0];
        float4 w1 = wv4[it * 48 + l * 3 + 1];
        float4 w2 = wv4[it * 48 + l * 3 + 2];
#pragma unroll
        for (int r = 0; r < 2; ++r) {
            float x0 = xv[r][it].x, x1 = xv[r][it].y;
            float x2 = xv[r][it].z, x3 = xv[r][it].w;
            kk[r] = fmaf(x0, w0.x, kk[r]);
            qq[r] = fmaf(x0, w0.y, qq[r]);
            vv[r] = fmaf(x0, w0.z, vv[r]);
            kk[r] = fmaf(x1, w0.w, kk[r]);
            qq[r] = fmaf(x1, w1.x, qq[r]);
            vv[r] = fmaf(x1, w1.y, vv[r]);
            kk[r] = fmaf(x2, w1.z, kk[r]);
            qq[r] = fmaf(x2, w1.w, qq[r]);
            vv[r] = fmaf(x2, w2.x, vv[r]);
            kk[r] = fmaf(x3, w2.y, kk[r]);
            qq[r] = fmaf(x3, w2.z, qq[r]);
            vv[r] = fmaf(x3, w2.w, vv[r]);
        }
    }

#pragma unroll
    for (int r = 0; r < 2; ++r) {
#pragma unroll
        for (int off = 8; off; off >>= 1) {
            kk[r] += __shfl_xor(kk[r], off, 64);
            qq[r] += __shfl_xor(qq[r], off, 64);
            vv[r] += __shfl_xor(vv[r], off, 64);
        }
        if (l == 0) {
            int node = node0 + r;
            kv[node] = make_float2(kk[r] + b0, vv[r] + b2);
            qg[node] = qq[r] + b1;
        }
    }
}

// ---------- kernel 2a: per-bucket edge counts (int4 loads, 1024 threads) ----------
__global__ __launch_bounds__(ETHREADS) void count_kernel(
    const int* __restrict__ ei0, const int* __restrict__ ei1,
    const int* __restrict__ ei2, unsigned* __restrict__ bucket_cnt)
{
    __shared__ unsigned hist[NBUK];
    int tid = threadIdx.x;
    if (tid < NBUK) hist[tid] = 0;
    __syncthreads();
    unsigned base = blockIdx.x * (unsigned)CHUNK;
    int t = (int)(base >> 20);
    unsigned i0 = base & (unsigned)(Ec - 1);
    const int* ei = (t == 0) ? ei0 : (t == 1) ? ei1 : ei2;
    int off = (t == 0) ? Nc : 0;
    const int4* dv = (const int4*)(ei + Ec + i0);
#pragma unroll
    for (int j = 0; j < CHUNK / (4 * ETHREADS); ++j) {    // 2 iters
        int4 d4 = dv[j * ETHREADS + tid];
        atomicAdd(&hist[(unsigned)(d4.x + off) >> 8], 1u);
        atomicAdd(&hist[(unsigned)(d4.y + off) >> 8], 1u);
        atomicAdd(&hist[(unsigned)(d4.z + off) >> 8], 1u);
        atomicAdd(&hist[(unsigned)(d4.w + off) >> 8], 1u);
    }
    __syncthreads();
    if (tid < NBUK) {
        unsigned h = hist[tid];
        if (h) atomicAdd(&bucket_cnt[tid], h);
    }
}

// ---------- kernel 2b: exclusive scan of bucket counts ----------
__global__ __launch_bounds__(NBUK) void scan_kernel(
    const unsigned* __restrict__ bucket_cnt,
    unsigned* __restrict__ bucket_base, unsigned* __restrict__ bucket_fill)
{
    __shared__ unsigned s[NBUK];
    int t = threadIdx.x;
    unsigned mine = bucket_cnt[t];
    s[t] = mine;
    __syncthreads();
    for (int off = 1; off < NBUK; off <<= 1) {
        unsigned v = (t >= off) ? s[t - off] : 0u;
        __syncthreads();
        s[t] += v;
        __syncthreads();
    }
    unsigned ex = s[t] - mine;
    bucket_base[t] = ex;
    bucket_fill[t] = ex;
    if (t == NBUK - 1) bucket_base[NBUK] = s[t];
}

// ---------- kernel 2c: scatter packed records into bucket order ----------
// record = s(16 bits) | t<<16 | (dg&255)<<18
// v4: CHUNK 8192 (long runs, proven write behavior) x 1024 threads (16 waves
// -> ~24 waves/CU vs r5's 6: latency hiding without fragmenting writes).
__global__ __launch_bounds__(ETHREADS) void fill_kernel(
    const int* __restrict__ ei0, const int* __restrict__ ei1,
    const int* __restrict__ ei2, unsigned* __restrict__ bucket_fill,
    unsigned* __restrict__ sorted)
{
    __shared__ unsigned hist[NBUK];
    __shared__ unsigned res[NBUK];
    int tid = threadIdx.x;
    if (tid < NBUK) hist[tid] = 0;
    __syncthreads();
    unsigned base = blockIdx.x * (unsigned)CHUNK;
    int t = (int)(base >> 20);
    unsigned i0 = base & (unsigned)(Ec - 1);
    const int* ei = (t == 0) ? ei0 : (t == 1) ? ei1 : ei2;
    int off = (t == 0) ? Nc : 0;
    const int4* dv = (const int4*)(ei + Ec + i0);
    const int4* sv = (const int4*)(ei + i0);
    int4 dreg[CHUNK / (4 * ETHREADS)];                    // 2 int4s
#pragma unroll
    for (int j = 0; j < CHUNK / (4 * ETHREADS); ++j) {
        int4 d4 = dv[j * ETHREADS + tid];
        dreg[j] = d4;
        atomicAdd(&hist[(unsigned)(d4.x + off) >> 8], 1u);
        atomicAdd(&hist[(unsigned)(d4.y + off) >> 8], 1u);
        atomicAdd(&hist[(unsigned)(d4.z + off) >> 8], 1u);
        atomicAdd(&hist[(unsigned)(d4.w + off) >> 8], 1u);
    }
    __syncthreads();
    if (tid < NBUK) {
        unsigned h = hist[tid];
        // res = absolute base slot for this block's run in bucket tid
        res[tid] = h ? atomicAdd(&bucket_fill[tid], h) : 0u;
    }
    __syncthreads();
#pragma unroll
    for (int j = 0; j < CHUNK / (4 * ETHREADS); ++j) {
        int4 d4 = dreg[j];
        int4 s4 = sv[j * ETHREADS + tid];
        int dd[4] = {d4.x, d4.y, d4.z, d4.w};
        int ss[4] = {s4.x, s4.y, s4.z, s4.w};
#pragma unroll
        for (int u = 0; u < 4; ++u) {
            int dg  = dd[u] + off;
            int bkt = dg >> 8;
            unsigned pos = atomicAdd(&res[bkt], 1u);  // returning LDS atomic
            sorted[pos] =
                (unsigned)ss[u] | ((unsigned)t << 16) | ((unsigned)(dg & 255) << 18);
        }
    }
}

// ---------- kernel 2d: per-bucket LDS accumulation (fp32, 2x replicated) ----------
__global__ __launch_bounds__(512) void bucket_accum_kernel(
    const unsigned* __restrict__ bucket_base, const unsigned* __restrict__ sorted,
    const float* __restrict__ krel_w, const float* __restrict__ krel_b,
    const float* __restrict__ vrel_w, const float* __restrict__ vrel_b,
    const float* __restrict__ p_rel,
    const float2* __restrict__ kv_i, const float2* __restrict__ kv_d,
    const float* __restrict__ q_glob,
    float* __restrict__ den, float* __restrict__ num)
{
    __shared__ float den_l[2 * BUKW];   // [dst][rep] interleaved: adjacent banks
    __shared__ float num_l[2 * BUKW];
    __shared__ float q_l[BUKW];
    int tid = threadIdx.x;
    int b   = blockIdx.x;
    den_l[tid] = 0.0f; num_l[tid] = 0.0f;      // 512 entries each
    if (tid < BUKW) q_l[tid] = q_glob[b * BUKW + tid];
    float kw0 = krel_w[0], kw1 = krel_w[1], kw2 = krel_w[2];
    float kb0 = krel_b[0], kb1 = krel_b[1], kb2 = krel_b[2];
    float vw0 = vrel_w[0], vw1 = vrel_w[1], vw2 = vrel_w[2];
    float vb0 = vrel_b[0], vb1 = vrel_b[1], vb2 = vrel_b[2];
    float pr0 = p_rel[0],  pr1 = p_rel[1],  pr2 = p_rel[2];
    unsigned beg = bucket_base[b], end = bucket_base[b + 1];
    int rep = tid & 1;
    __syncthreads();

    for (unsigned e = beg + tid; e < end; e += 512) {
        unsigned r = sorted[e];
        int s    = (int)(r & 0xFFFFu);
        int t    = (int)((r >> 16) & 3u);
        int low8 = (int)((r >> 18) & 255u);
        float2 kvv = (t == 1) ? kv_d[s] : kv_i[s];
        float kwt = (t == 0) ? kw0 : (t == 1) ? kw1 : kw2;
        float kbt = (t == 0) ? kb0 : (t == 1) ? kb1 : kb2;
        float vwt = (t == 0) ? vw0 : (t == 1) ? vw1 : vw2;
        float vbt = (t == 0) ? vb0 : (t == 1) ? vb1 : vb2;
        float prt = (t == 0) ? pr0 : (t == 1) ? pr1 : pr2;
        float ke = fmaf(kvv.x, kwt, kbt);
        float ve = fmaf(kvv.y, vwt, vbt);
        float logit = q_l[low8] * ke * prt;
        float ex = __expf(fminf(logit, 80.0f));
        int slot = low8 * 2 + rep;
        __hip_atomic_fetch_add(&den_l[slot], ex, __ATOMIC_RELAXED,
                               __HIP_MEMORY_SCOPE_WORKGROUP);
        __hip_atomic_fetch_add(&num_l[slot], ex * ve, __ATOMIC_RELAXED,
                               __HIP_MEMORY_SCOPE_WORKGROUP);
    }
    __syncthreads();
    if (tid < BUKW) {
        den[b * BUKW + tid] = den_l[tid * 2] + den_l[tid * 2 + 1];
        num[b * BUKW + tid] = num_l[tid * 2] + num_l[tid * 2 + 1];
    }
}

// ---------- kernel 3: score + 2-level radix top-K (u32 keys) ----------
__global__ __launch_bounds__(1024) void select_kernel(
    const float* __restrict__ den, const float* __restrict__ num,
    const float* __restrict__ w_out_inst, const float* __restrict__ b_out_inst,
    const float* __restrict__ w_out_data, const float* __restrict__ b_out_data,
    int* __restrict__ sel_idx, float* __restrict__ sel_w)
{
    __shared__ unsigned keys[NPGc];             // 16 KB
    __shared__ unsigned hist[2048];             // 8 KB
    __shared__ unsigned wsum[16];
    __shared__ unsigned short cand[NPGc];       // 8 KB
    __shared__ unsigned sh_bin1, sh_rem1, sh_bin2, sh_rem2, sh_cnt, sh_nc;

    int tid  = threadIdx.x;
    int seg  = blockIdx.x;          // 0..31
    int side = seg >> 4;
    int b    = seg & 15;
    float wo = side ? w_out_data[0] : w_out_inst[0];
    float bo = side ? b_out_data[0] : b_out_inst[0];
    int base_node = side * Nc + b * NPGc;
    int base_sel  = seg * Kc;

    unsigned myk[4]; int myj[4];
#pragma unroll
    for (int p = 0; p < 4; ++p) {
        int j = p * 1024 + tid;
        float dn = den[base_node + j];
        float a  = (dn > 0.0f) ? num[base_node + j] / dn : 0.0f;
        float z  = fmaf(a, wo, bo);
        float s  = 0.5f * z * (1.0f + erff(z * 0.70710678f));
        unsigned k32 = fkey(s);
        keys[j] = k32; myk[p] = k32; myj[p] = j;
    }
    if (tid == 0) { sh_cnt = 0; sh_nc = 0; }
    hist[tid] = 0; hist[tid + 1024] = 0;
    __syncthreads();

    // phase 1: hist over bits [31:21]
#pragma unroll
    for (int p = 0; p < 4; ++p) atomicAdd(&hist[myk[p] >> 21], 1u);
    __syncthreads();
    {
        unsigned g0 = hist[2047 - 2 * tid];
        unsigned g1 = hist[2046 - 2 * tid];
        unsigned x = g0 + g1;
        int lane = tid & 63;
#pragma unroll
        for (int off = 1; off < 64; off <<= 1) {
            unsigned y = __shfl_up(x, off, 64);
            if (lane >= off) x += y;
        }
        if (lane == 63) wsum[tid >> 6] = x;
        __syncthreads();
        if (tid < 16) {
            unsigned v = wsum[tid];
#pragma unroll
            for (int off = 1; off < 16; off <<= 1) {
                unsigned y = __shfl_up(v, off, 64);
                if (tid >= off) v += y;
            }
            wsum[tid] = v;
        }
        __syncthreads();
        unsigned basew = (tid >= 64) ? wsum[(tid >> 6) - 1] : 0u;
        unsigned incl  = basew + x;
        unsigned incl0 = incl - g1;
        unsigned K = Kc;
        if (incl0 >= K && incl0 - g0 < K) { sh_bin1 = 2047 - 2 * tid; sh_rem1 = K - (incl0 - g0); }
        if (incl  >= K && incl0     < K) { sh_bin1 = 2046 - 2 * tid; sh_rem1 = K - incl0; }
    }
    __syncthreads();
    unsigned bin1 = sh_bin1, rem1 = sh_rem1;
    hist[tid] = 0; hist[tid + 1024] = 0;
    __syncthreads();

    // phase 2: hist over bits [20:10] among bin1 keys
#pragma unroll
    for (int p = 0; p < 4; ++p)
        if ((myk[p] >> 21) == bin1)
            atomicAdd(&hist[(myk[p] >> 10) & 2047u], 1u);
    __syncthreads();
    {
        unsigned g0 = hist[2047 - 2 * tid];
        unsigned g1 = hist[2046 - 2 * tid];
        unsigned x = g0 + g1;
        int lane = tid & 63;
#pragma unroll
        for (int off = 1; off < 64; off <<= 1) {
            unsigned y = __shfl_up(x, off, 64);
            if (lane >= off) x += y;
        }
        if (lane == 63) wsum[tid >> 6] = x;
        __syncthreads();
        if (tid < 16) {
            unsigned v = wsum[tid];
#pragma unroll
            for (int off = 1; off < 16; off <<= 1) {
                unsigned y = __shfl_up(v, off, 64);
                if (tid >= off) v += y;
            }
            wsum[tid] = v;
        }
        __syncthreads();
        unsigned basew = (tid >= 64) ? wsum[(tid >> 6) - 1] : 0u;
        unsigned incl  = basew + x;
        unsigned incl0 = incl - g1;
        unsigned K = rem1;
        if (incl0 >= K && incl0 - g0 < K) { sh_bin2 = 2047 - 2 * tid; sh_rem2 = K - (incl0 - g0); }
        if (incl  >= K && incl0     < K) { sh_bin2 = 2046 - 2 * tid; sh_rem2 = K - incl0; }
    }
    __syncthreads();
    unsigned pref22 = (bin1 << 11) | sh_bin2;
    unsigned rem2 = sh_rem2;

    // phase 3: classify
#pragma unroll
    for (int p = 0; p < 4; ++p) {
        unsigned top22 = myk[p] >> 10;
        if (top22 > pref22) {
            unsigned pos = atomicAdd(&sh_cnt, 1u);
            sel_idx[base_sel + pos] = myj[p];
            sel_w[base_sel + pos]   = tanhf(inv_fkey(myk[p]));
        } else if (top22 == pref22) {
            unsigned cp = atomicAdd(&sh_nc, 1u);
            cand[cp] = (unsigned short)myj[p];
        }
    }
    __syncthreads();

    // phase 4: exact rank among candidates (key desc, index asc)
    unsigned nc = sh_nc;
    for (unsigned c = tid; c < nc; c += 1024) {
        int j = cand[c];
        unsigned k32 = keys[j];
        unsigned rank = 0;
        for (unsigned q = 0; q < nc; ++q) {
            int jq = cand[q];
            unsigned kq = keys[jq];
            rank += (kq > k32 || (kq == k32 && jq < j)) ? 1u : 0u;
        }
        if (rank < rem2) {
            unsigned pos = atomicAdd(&sh_cnt, 1u);
            sel_idx[base_sel + pos] = j;
            sel_w[base_sel + pos]   = tanhf(inv_fkey(k32));
        }
    }
}

// ---------- kernel 4: weighted mean of selected rows ----------
__global__ __launch_bounds__(1024) void pool_kernel(
    const float* __restrict__ x_inst, const float* __restrict__ x_data,
    const int* __restrict__ sel_idx, const float* __restrict__ sel_w,
    float* __restrict__ out)
{
    __shared__ int   ridx[64];
    __shared__ float rw[64];
    __shared__ float accs[256];
    int tid   = threadIdx.x;
    int blk   = blockIdx.x;
    int seg   = blk >> 4;
    int chunk = blk & 15;
    int side  = seg >> 4;
    int b     = seg & 15;
    if (tid < 64) {
        ridx[tid] = sel_idx[seg * Kc + chunk * 64 + tid];
        rw[tid]   = sel_w[seg * Kc + chunk * 64 + tid];
    }
    if (tid < 256) accs[tid] = 0.0f;
    __syncthreads();
    const float* x = side ? x_data : x_inst;
    int w = tid >> 6, l = tid & 63;
    float ax = 0.f, ay = 0.f, az = 0.f, aw = 0.f;
#pragma unroll
    for (int r = 0; r < 4; ++r) {
        int   row = ridx[w * 4 + r];
        float wt  = rw[w * 4 + r];
        float4 xv = ((const float4*)(x + ((size_t)(b * NPGc + row)) * Cc))[l];
        ax = fmaf(xv.x, wt, ax); ay = fmaf(xv.y, wt, ay);
        az = fmaf(xv.z, wt, az); aw = fmaf(xv.w, wt, aw);
    }
    atomicAdd(&accs[l * 4 + 0], ax);
    atomicAdd(&accs[l * 4 + 1], ay);
    atomicAdd(&accs[l * 4 + 2], az);
    atomicAdd(&accs[l * 4 + 3], aw);
    __syncthreads();
    if (tid < 256)
        unsafeAtomicAdd(&out[b * 512 + side * 256 + tid], accs[tid] * (1.0f / (float)Kc));
}

extern "C" void kernel_launch(void* const* d_in, const int* in_sizes, int n_in,
                              void* d_out, int out_size, void* d_ws, size_t ws_size,
                              hipStream_t stream) {
    const float* x_inst     = (const float*)d_in[0];
    const float* x_data     = (const float*)d_in[1];
    const float* w_kqv_inst = (const float*)d_in[2];
    const float* b_kqv_inst = (const float*)d_in[3];
    const float* w_kqv_data = (const float*)d_in[4];
    const float* b_kqv_data = (const float*)d_in[5];
    const float* w_out_inst = (const float*)d_in[6];
    const float* b_out_inst = (const float*)d_in[7];
    const float* w_out_data = (const float*)d_in[8];
    const float* b_out_data = (const float*)d_in[9];
    const float* krel_w     = (const float*)d_in[10];
    const float* krel_b     = (const float*)d_in[11];
    const float* vrel_w     = (const float*)d_in[12];
    const float* vrel_b     = (const float*)d_in[13];
    const float* p_rel      = (const float*)d_in[14];
    const int*   ei_i2d     = (const int*)d_in[15];
    const int*   ei_d2i     = (const int*)d_in[16];
    const int*   ei_i2i     = (const int*)d_in[17];
    float* out = (float*)d_out;

    // workspace layout (fp32) — ~15.4 MB
    char* ws = (char*)d_ws;
    float2* kv_i   = (float2*)ws;                        // N
    float2* kv_d   = kv_i + Nc;                          // N
    float*  q_glob = (float*)(kv_d + Nc);                // 2N
    float*  den    = q_glob + 2 * Nc;                    // 2N
    float*  num    = den + 2 * Nc;                       // 2N
    unsigned* bucket_cnt  = (unsigned*)(num + 2 * Nc);   // NBUK
    unsigned* bucket_base = bucket_cnt + NBUK;           // NBUK+1
    unsigned* bucket_fill = bucket_base + NBUK + 1;      // NBUK
    int*      sel_idx     = (int*)(bucket_fill + NBUK);  // 32*K
    float*    sel_w       = (float*)(sel_idx + 32 * Kc); // 32*K
    unsigned* sorted      = (unsigned*)(sel_w + 32 * Kc);// 3E (12.6 MB)

    hipMemsetAsync(bucket_cnt, 0, NBUK * sizeof(unsigned), stream);
    hipMemsetAsync(d_out, 0, (size_t)out_size * sizeof(float), stream);

    // edge path (independent of x): count -> scan -> fill
    count_kernel<<<NCHUNK, ETHREADS, 0, stream>>>(ei_i2d, ei_d2i, ei_i2i, bucket_cnt);
    scan_kernel<<<1, NBUK, 0, stream>>>(bucket_cnt, bucket_base, bucket_fill);
    fill_kernel<<<NCHUNK, ETHREADS, 0, stream>>>(ei_i2d, ei_d2i, ei_i2i,
                                                 bucket_fill, sorted);

    // kqv per side: 32 rows per block, 2048 blocks each
    kqv_side_kernel<<<Nc / 32, 256, 0, stream>>>(
        x_inst, w_kqv_inst, b_kqv_inst, kv_i, q_glob);
    kqv_side_kernel<<<Nc / 32, 256, 0, stream>>>(
        x_data, w_kqv_data, b_kqv_data, kv_d, q_glob + Nc);

    // per-bucket LDS accumulate: 512 blocks x 512 threads
    bucket_accum_kernel<<<NBUK, 512, 0, stream>>>(
        bucket_base, sorted,
        krel_w, krel_b, vrel_w, vrel_b, p_rel,
        kv_i, kv_d, q_glob, den, num);

    // score + top-K select
    select_kernel<<<32, 1024, 0, stream>>>(
        den, num, w_out_inst, b_out_inst, w_out_data, b_out_data,
        sel_idx, sel_w);

    // pooled weighted mean
    pool_kernel<<<512, 1024, 0, stream>>>(x_inst, x_data, sel_idx, sel_w, out);
}

// Round 9
// 290.414 us; speedup vs baseline: 1.1558x; 1.0365x over previous
//
#include <hip/hip_runtime.h>
#include <math.h>

// Problem constants
constexpr int BB   = 16;
constexpr int NPGc = 4096;
constexpr int Cc   = 256;
constexpr int Nc   = BB * NPGc;      // 65536
constexpr int Ec   = Nc * 16;        // 1048576 = 1<<20
constexpr int Kc   = 1024;           // ceil(0.25*4096)
constexpr int NBUK = 512;            // dst buckets
constexpr int BUKW = 256;            // dst per bucket (2N / NBUK)
// Bucket load is ASYMMETRIC (r8 failure): t=1,2 -> buckets 0..255 (mean 8192),
// t=0 -> buckets 256..511 (mean 4096). Capacities sized per region.
constexpr int CAP_LO = 10240;        // buckets 0..255: mean 8192, sd~88 -> +23 sigma
constexpr int CAP_HI = 6144;         // buckets 256..511: mean 4096, sd~63 -> +32 sigma
constexpr unsigned LO_TOT = 256u * CAP_LO;   // 2621440
// total sorted = 4194304 records = 16.8 MB (same footprint r8 ran with)
constexpr int CHUNK = 8192;          // edges per fill block (best write coalescing, r6)
constexpr int NCHUNK = (3 * Ec) / CHUNK;   // 384
constexpr int ETHREADS = 1024;       // 16 waves/block (occupancy decoupled from chunk, r7)

__device__ __forceinline__ unsigned bkt_base(int bkt) {
    return (bkt < 256) ? (unsigned)bkt * CAP_LO
                       : LO_TOT + (unsigned)(bkt - 256) * CAP_HI;
}
__device__ __forceinline__ unsigned bkt_cap(int bkt) {
    return (bkt < 256) ? (unsigned)CAP_LO : (unsigned)CAP_HI;
}

// ---------- monotonic float <-> u32 key ----------
__device__ __forceinline__ unsigned fkey(float f) {
    int b = __float_as_int(f);
    unsigned u = (unsigned)b;
    return (b < 0) ? ~u : (u | 0x80000000u);
}
__device__ __forceinline__ float inv_fkey(unsigned u) {
    unsigned b = (u & 0x80000000u) ? (u ^ 0x80000000u) : ~u;
    return __int_as_float((int)b);
}

// ---------- kernel 1: kqv = x @ w + b (fp32), ONE SIDE per dispatch ----------
// Round-3 proven body (VGPR 52, ~23.5us/side).
__global__ __launch_bounds__(256) void kqv_side_kernel(
    const float* __restrict__ x, const float* __restrict__ w,
    const float* __restrict__ bp,
    float2* __restrict__ kv, float* __restrict__ qg)
{
    __shared__ float wls[768];                     // 256x3 weights, 3 KB
    int tid  = threadIdx.x;
    int wave = tid >> 6, lane = tid & 63;
    int grp  = lane >> 4, l = lane & 15;
    int g    = blockIdx.x * 16 + wave * 4 + grp;   // group id, 2 rows each
    int node0 = g * 2;                             // 0..N-1

    if (tid < 192)
        ((float4*)wls)[tid] = ((const float4*)w)[tid];
    float b0 = bp[0], b1 = bp[1], b2 = bp[2];
    __syncthreads();

    // all 8 x-loads issued up front (32 VGPRs of payload)
    const float4* rp = (const float4*)(x + (size_t)node0 * Cc);
    float4 xv[2][4];
#pragma unroll
    for (int r = 0; r < 2; ++r)
#pragma unroll
        for (int it = 0; it < 4; ++it)
            xv[r][it] = rp[r * 64 + it * 16 + l];

    float kk[2] = {0.f, 0.f};
    float qq[2] = {0.f, 0.f};
    float vv[2] = {0.f, 0.f};
    const float4* wv4 = (const float4*)wls;
#pragma unroll
    for (int it = 0; it < 4; ++it) {
        float4 w0 = wv4[it * 48 + l * 3 + 0];
        float4 w1 = wv4[it * 48 + l * 3 + 1];
        float4 w2 = wv4[it * 48 + l * 3 + 2];
#pragma unroll
        for (int r = 0; r < 2; ++r) {
            float x0 = xv[r][it].x, x1 = xv[r][it].y;
            float x2 = xv[r][it].z, x3 = xv[r][it].w;
            kk[r] = fmaf(x0, w0.x, kk[r]);
            qq[r] = fmaf(x0, w0.y, qq[r]);
            vv[r] = fmaf(x0, w0.z, vv[r]);
            kk[r] = fmaf(x1, w0.w, kk[r]);
            qq[r] = fmaf(x1, w1.x, qq[r]);
            vv[r] = fmaf(x1, w1.y, vv[r]);
            kk[r] = fmaf(x2, w1.z, kk[r]);
            qq[r] = fmaf(x2, w1.w, qq[r]);
            vv[r] = fmaf(x2, w2.x, vv[r]);
            kk[r] = fmaf(x3, w2.y, kk[r]);
            qq[r] = fmaf(x3, w2.z, qq[r]);
            vv[r] = fmaf(x3, w2.w, vv[r]);
        }
    }

#pragma unroll
    for (int r = 0; r < 2; ++r) {
#pragma unroll
        for (int off = 8; off; off >>= 1) {
            kk[r] += __shfl_xor(kk[r], off, 64);
            qq[r] += __shfl_xor(qq[r], off, 64);
            vv[r] += __shfl_xor(vv[r], off, 64);
        }
        if (l == 0) {
            int node = node0 + r;
            kv[node] = make_float2(kk[r] + b0, vv[r] + b2);
            qg[node] = qq[r] + b1;
        }
    }
}

// ---------- kernel 2: single-pass scatter into capacity buckets ----------
// Replaces count+scan+fill. sorted[bkt_base(bkt) + i]; bucket_fill[bkt] = count.
// record = s(16 bits) | t<<16 | (dg&255)<<18
__global__ __launch_bounds__(ETHREADS) void fill_kernel(
    const int* __restrict__ ei0, const int* __restrict__ ei1,
    const int* __restrict__ ei2, unsigned* __restrict__ bucket_fill,
    unsigned* __restrict__ sorted)
{
    __shared__ unsigned hist[NBUK];
    __shared__ unsigned res[NBUK];
    int tid = threadIdx.x;
    if (tid < NBUK) hist[tid] = 0;
    __syncthreads();
    unsigned base = blockIdx.x * (unsigned)CHUNK;
    int t = (int)(base >> 20);
    unsigned i0 = base & (unsigned)(Ec - 1);
    const int* ei = (t == 0) ? ei0 : (t == 1) ? ei1 : ei2;
    int off = (t == 0) ? Nc : 0;
    const int4* dv = (const int4*)(ei + Ec + i0);
    const int4* sv = (const int4*)(ei + i0);
    int4 dreg[CHUNK / (4 * ETHREADS)];                    // 2 int4s
#pragma unroll
    for (int j = 0; j < CHUNK / (4 * ETHREADS); ++j) {
        int4 d4 = dv[j * ETHREADS + tid];
        dreg[j] = d4;
        atomicAdd(&hist[(unsigned)(d4.x + off) >> 8], 1u);
        atomicAdd(&hist[(unsigned)(d4.y + off) >> 8], 1u);
        atomicAdd(&hist[(unsigned)(d4.z + off) >> 8], 1u);
        atomicAdd(&hist[(unsigned)(d4.w + off) >> 8], 1u);
    }
    __syncthreads();
    if (tid < NBUK) {
        unsigned h = hist[tid];
        // absolute base slot for this block's run in bucket tid
        res[tid] = h ? (bkt_base(tid) + atomicAdd(&bucket_fill[tid], h)) : 0u;
    }
    __syncthreads();
#pragma unroll
    for (int j = 0; j < CHUNK / (4 * ETHREADS); ++j) {
        int4 d4 = dreg[j];
        int4 s4 = sv[j * ETHREADS + tid];
        int dd[4] = {d4.x, d4.y, d4.z, d4.w};
        int ss[4] = {s4.x, s4.y, s4.z, s4.w};
#pragma unroll
        for (int u = 0; u < 4; ++u) {
            int dg  = dd[u] + off;
            int bkt = dg >> 8;
            unsigned pos = atomicAdd(&res[bkt], 1u);      // returning LDS atomic
            if (pos < bkt_base(bkt) + bkt_cap(bkt))       // ~23-32 sigma guard
                sorted[pos] = (unsigned)ss[u] | ((unsigned)t << 16)
                            | ((unsigned)(dg & 255) << 18);
        }
    }
}

// ---------- kernel 3: per-bucket LDS accumulation (fp32, 2x replicated) ----------
__global__ __launch_bounds__(512) void bucket_accum_kernel(
    const unsigned* __restrict__ bucket_cnt, const unsigned* __restrict__ sorted,
    const float* __restrict__ krel_w, const float* __restrict__ krel_b,
    const float* __restrict__ vrel_w, const float* __restrict__ vrel_b,
    const float* __restrict__ p_rel,
    const float2* __restrict__ kv_i, const float2* __restrict__ kv_d,
    const float* __restrict__ q_glob,
    float* __restrict__ den, float* __restrict__ num)
{
    __shared__ float den_l[2 * BUKW];   // [dst][rep] interleaved: adjacent banks
    __shared__ float num_l[2 * BUKW];
    __shared__ float q_l[BUKW];
    int tid = threadIdx.x;
    int b   = blockIdx.x;
    den_l[tid] = 0.0f; num_l[tid] = 0.0f;      // 512 entries each
    if (tid < BUKW) q_l[tid] = q_glob[b * BUKW + tid];
    float kw0 = krel_w[0], kw1 = krel_w[1], kw2 = krel_w[2];
    float kb0 = krel_b[0], kb1 = krel_b[1], kb2 = krel_b[2];
    float vw0 = vrel_w[0], vw1 = vrel_w[1], vw2 = vrel_w[2];
    float vb0 = vrel_b[0], vb1 = vrel_b[1], vb2 = vrel_b[2];
    float pr0 = p_rel[0],  pr1 = p_rel[1],  pr2 = p_rel[2];
    unsigned cnt = bucket_cnt[b];
    unsigned cap = bkt_cap(b);
    if (cnt > cap) cnt = cap;
    unsigned beg = bkt_base(b), end = beg + cnt;
    int rep = tid & 1;
    __syncthreads();

    for (unsigned e = beg + tid; e < end; e += 512) {
        unsigned r = sorted[e];
        int s    = (int)(r & 0xFFFFu);
        int t    = (int)((r >> 16) & 3u);
        int low8 = (int)((r >> 18) & 255u);
        float2 kvv = (t == 1) ? kv_d[s] : kv_i[s];
        float kwt = (t == 0) ? kw0 : (t == 1) ? kw1 : kw2;
        float kbt = (t == 0) ? kb0 : (t == 1) ? kb1 : kb2;
        float vwt = (t == 0) ? vw0 : (t == 1) ? vw1 : vw2;
        float vbt = (t == 0) ? vb0 : (t == 1) ? vb1 : vb2;
        float prt = (t == 0) ? pr0 : (t == 1) ? pr1 : pr2;
        float ke = fmaf(kvv.x, kwt, kbt);
        float ve = fmaf(kvv.y, vwt, vbt);
        float logit = q_l[low8] * ke * prt;
        float ex = __expf(fminf(logit, 80.0f));
        int slot = low8 * 2 + rep;
        __hip_atomic_fetch_add(&den_l[slot], ex, __ATOMIC_RELAXED,
                               __HIP_MEMORY_SCOPE_WORKGROUP);
        __hip_atomic_fetch_add(&num_l[slot], ex * ve, __ATOMIC_RELAXED,
                               __HIP_MEMORY_SCOPE_WORKGROUP);
    }
    __syncthreads();
    if (tid < BUKW) {
        den[b * BUKW + tid] = den_l[tid * 2] + den_l[tid * 2 + 1];
        num[b * BUKW + tid] = num_l[tid * 2] + num_l[tid * 2 + 1];
    }
}

// ---------- kernel 4: score + 2-level radix top-K (u32 keys) ----------
__global__ __launch_bounds__(1024) void select_kernel(
    const float* __restrict__ den, const float* __restrict__ num,
    const float* __restrict__ w_out_inst, const float* __restrict__ b_out_inst,
    const float* __restrict__ w_out_data, const float* __restrict__ b_out_data,
    int* __restrict__ sel_idx, float* __restrict__ sel_w)
{
    __shared__ unsigned keys[NPGc];             // 16 KB
    __shared__ unsigned hist[2048];             // 8 KB
    __shared__ unsigned wsum[16];
    __shared__ unsigned short cand[NPGc];       // 8 KB
    __shared__ unsigned sh_bin1, sh_rem1, sh_bin2, sh_rem2, sh_cnt, sh_nc;

    int tid  = threadIdx.x;
    int seg  = blockIdx.x;          // 0..31
    int side = seg >> 4;
    int b    = seg & 15;
    float wo = side ? w_out_data[0] : w_out_inst[0];
    float bo = side ? b_out_data[0] : b_out_inst[0];
    int base_node = side * Nc + b * NPGc;
    int base_sel  = seg * Kc;

    unsigned myk[4]; int myj[4];
#pragma unroll
    for (int p = 0; p < 4; ++p) {
        int j = p * 1024 + tid;
        float dn = den[base_node + j];
        float a  = (dn > 0.0f) ? num[base_node + j] / dn : 0.0f;
        float z  = fmaf(a, wo, bo);
        float s  = 0.5f * z * (1.0f + erff(z * 0.70710678f));
        unsigned k32 = fkey(s);
        keys[j] = k32; myk[p] = k32; myj[p] = j;
    }
    if (tid == 0) { sh_cnt = 0; sh_nc = 0; }
    hist[tid] = 0; hist[tid + 1024] = 0;
    __syncthreads();

    // phase 1: hist over bits [31:21]
#pragma unroll
    for (int p = 0; p < 4; ++p) atomicAdd(&hist[myk[p] >> 21], 1u);
    __syncthreads();
    {
        unsigned g0 = hist[2047 - 2 * tid];
        unsigned g1 = hist[2046 - 2 * tid];
        unsigned x = g0 + g1;
        int lane = tid & 63;
#pragma unroll
        for (int off = 1; off < 64; off <<= 1) {
            unsigned y = __shfl_up(x, off, 64);
            if (lane >= off) x += y;
        }
        if (lane == 63) wsum[tid >> 6] = x;
        __syncthreads();
        if (tid < 16) {
            unsigned v = wsum[tid];
#pragma unroll
            for (int off = 1; off < 16; off <<= 1) {
                unsigned y = __shfl_up(v, off, 64);
                if (tid >= off) v += y;
            }
            wsum[tid] = v;
        }
        __syncthreads();
        unsigned basew = (tid >= 64) ? wsum[(tid >> 6) - 1] : 0u;
        unsigned incl  = basew + x;
        unsigned incl0 = incl - g1;
        unsigned K = Kc;
        if (incl0 >= K && incl0 - g0 < K) { sh_bin1 = 2047 - 2 * tid; sh_rem1 = K - (incl0 - g0); }
        if (incl  >= K && incl0     < K) { sh_bin1 = 2046 - 2 * tid; sh_rem1 = K - incl0; }
    }
    __syncthreads();
    unsigned bin1 = sh_bin1, rem1 = sh_rem1;
    hist[tid] = 0; hist[tid + 1024] = 0;
    __syncthreads();

    // phase 2: hist over bits [20:10] among bin1 keys
#pragma unroll
    for (int p = 0; p < 4; ++p)
        if ((myk[p] >> 21) == bin1)
            atomicAdd(&hist[(myk[p] >> 10) & 2047u], 1u);
    __syncthreads();
    {
        unsigned g0 = hist[2047 - 2 * tid];
        unsigned g1 = hist[2046 - 2 * tid];
        unsigned x = g0 + g1;
        int lane = tid & 63;
#pragma unroll
        for (int off = 1; off < 64; off <<= 1) {
            unsigned y = __shfl_up(x, off, 64);
            if (lane >= off) x += y;
        }
        if (lane == 63) wsum[tid >> 6] = x;
        __syncthreads();
        if (tid < 16) {
            unsigned v = wsum[tid];
#pragma unroll
            for (int off = 1; off < 16; off <<= 1) {
                unsigned y = __shfl_up(v, off, 64);
                if (tid >= off) v += y;
            }
            wsum[tid] = v;
        }
        __syncthreads();
        unsigned basew = (tid >= 64) ? wsum[(tid >> 6) - 1] : 0u;
        unsigned incl  = basew + x;
        unsigned incl0 = incl - g1;
        unsigned K = rem1;
        if (incl0 >= K && incl0 - g0 < K) { sh_bin2 = 2047 - 2 * tid; sh_rem2 = K - (incl0 - g0); }
        if (incl  >= K && incl0     < K) { sh_bin2 = 2046 - 2 * tid; sh_rem2 = K - incl0; }
    }
    __syncthreads();
    unsigned pref22 = (bin1 << 11) | sh_bin2;
    unsigned rem2 = sh_rem2;

    // phase 3: classify
#pragma unroll
    for (int p = 0; p < 4; ++p) {
        unsigned top22 = myk[p] >> 10;
        if (top22 > pref22) {
            unsigned pos = atomicAdd(&sh_cnt, 1u);
            sel_idx[base_sel + pos] = myj[p];
            sel_w[base_sel + pos]   = tanhf(inv_fkey(myk[p]));
        } else if (top22 == pref22) {
            unsigned cp = atomicAdd(&sh_nc, 1u);
            cand[cp] = (unsigned short)myj[p];
        }
    }
    __syncthreads();

    // phase 4: exact rank among candidates (key desc, index asc)
    unsigned nc = sh_nc;
    for (unsigned c = tid; c < nc; c += 1024) {
        int j = cand[c];
        unsigned k32 = keys[j];
        unsigned rank = 0;
        for (unsigned q = 0; q < nc; ++q) {
            int jq = cand[q];
            unsigned kq = keys[jq];
            rank += (kq > k32 || (kq == k32 && jq < j)) ? 1u : 0u;
        }
        if (rank < rem2) {
            unsigned pos = atomicAdd(&sh_cnt, 1u);
            sel_idx[base_sel + pos] = j;
            sel_w[base_sel + pos]   = tanhf(inv_fkey(k32));
        }
    }
}

// ---------- kernel 5: weighted mean of selected rows ----------
__global__ __launch_bounds__(1024) void pool_kernel(
    const float* __restrict__ x_inst, const float* __restrict__ x_data,
    const int* __restrict__ sel_idx, const float* __restrict__ sel_w,
    float* __restrict__ out)
{
    __shared__ int   ridx[64];
    __shared__ float rw[64];
    __shared__ float accs[256];
    int tid   = threadIdx.x;
    int blk   = blockIdx.x;
    int seg   = blk >> 4;
    int chunk = blk & 15;
    int side  = seg >> 4;
    int b     = seg & 15;
    if (tid < 64) {
        ridx[tid] = sel_idx[seg * Kc + chunk * 64 + tid];
        rw[tid]   = sel_w[seg * Kc + chunk * 64 + tid];
    }
    if (tid < 256) accs[tid] = 0.0f;
    __syncthreads();
    const float* x = side ? x_data : x_inst;
    int w = tid >> 6, l = tid & 63;
    float ax = 0.f, ay = 0.f, az = 0.f, aw = 0.f;
#pragma unroll
    for (int r = 0; r < 4; ++r) {
        int   row = ridx[w * 4 + r];
        float wt  = rw[w * 4 + r];
        float4 xv = ((const float4*)(x + ((size_t)(b * NPGc + row)) * Cc))[l];
        ax = fmaf(xv.x, wt, ax); ay = fmaf(xv.y, wt, ay);
        az = fmaf(xv.z, wt, az); aw = fmaf(xv.w, wt, aw);
    }
    atomicAdd(&accs[l * 4 + 0], ax);
    atomicAdd(&accs[l * 4 + 1], ay);
    atomicAdd(&accs[l * 4 + 2], az);
    atomicAdd(&accs[l * 4 + 3], aw);
    __syncthreads();
    if (tid < 256)
        unsafeAtomicAdd(&out[b * 512 + side * 256 + tid], accs[tid] * (1.0f / (float)Kc));
}

extern "C" void kernel_launch(void* const* d_in, const int* in_sizes, int n_in,
                              void* d_out, int out_size, void* d_ws, size_t ws_size,
                              hipStream_t stream) {
    const float* x_inst     = (const float*)d_in[0];
    const float* x_data     = (const float*)d_in[1];
    const float* w_kqv_inst = (const float*)d_in[2];
    const float* b_kqv_inst = (const float*)d_in[3];
    const float* w_kqv_data = (const float*)d_in[4];
    const float* b_kqv_data = (const float*)d_in[5];
    const float* w_out_inst = (const float*)d_in[6];
    const float* b_out_inst = (const float*)d_in[7];
    const float* w_out_data = (const float*)d_in[8];
    const float* b_out_data = (const float*)d_in[9];
    const float* krel_w     = (const float*)d_in[10];
    const float* krel_b     = (const float*)d_in[11];
    const float* vrel_w     = (const float*)d_in[12];
    const float* vrel_b     = (const float*)d_in[13];
    const float* p_rel      = (const float*)d_in[14];
    const int*   ei_i2d     = (const int*)d_in[15];
    const int*   ei_d2i     = (const int*)d_in[16];
    const int*   ei_i2i     = (const int*)d_in[17];
    float* out = (float*)d_out;

    // workspace layout (fp32) — ~19.5 MB
    char* ws = (char*)d_ws;
    float2* kv_i   = (float2*)ws;                        // N
    float2* kv_d   = kv_i + Nc;                          // N
    float*  q_glob = (float*)(kv_d + Nc);                // 2N
    float*  den    = q_glob + 2 * Nc;                    // 2N
    float*  num    = den + 2 * Nc;                       // 2N
    unsigned* bucket_fill = (unsigned*)(num + 2 * Nc);   // NBUK (counts)
    int*      sel_idx     = (int*)(bucket_fill + NBUK);  // 32*K
    float*    sel_w       = (float*)(sel_idx + 32 * Kc); // 32*K
    unsigned* sorted      = (unsigned*)(sel_w + 32 * Kc);// 4194304 (16.8 MB)

    hipMemsetAsync(bucket_fill, 0, NBUK * sizeof(unsigned), stream);
    hipMemsetAsync(d_out, 0, (size_t)out_size * sizeof(float), stream);

    // edge path: single-pass scatter into capacity buckets (count+scan deleted)
    fill_kernel<<<NCHUNK, ETHREADS, 0, stream>>>(ei_i2d, ei_d2i, ei_i2i,
                                                 bucket_fill, sorted);

    // kqv per side: 32 rows per block, 2048 blocks each
    kqv_side_kernel<<<Nc / 32, 256, 0, stream>>>(
        x_inst, w_kqv_inst, b_kqv_inst, kv_i, q_glob);
    kqv_side_kernel<<<Nc / 32, 256, 0, stream>>>(
        x_data, w_kqv_data, b_kqv_data, kv_d, q_glob + Nc);

    // per-bucket LDS accumulate: 512 blocks x 512 threads
    bucket_accum_kernel<<<NBUK, 512, 0, stream>>>(
        bucket_fill, sorted,
        krel_w, krel_b, vrel_w, vrel_b, p_rel,
        kv_i, kv_d, q_glob, den, num);

    // score + top-K select
    select_kernel<<<32, 1024, 0, stream>>>(
        den, num, w_out_inst, b_out_inst, w_out_data, b_out_data,
        sel_idx, sel_w);

    // pooled weighted mean
    pool_kernel<<<512, 1024, 0, stream>>>(x_inst, x_data, sel_idx, sel_w, out);
}